// Round 3
// baseline (310.430 us; speedup 1.0000x reference)
//
#include <hip/hip_runtime.h>
#include <math.h>

#define SLEN 8000
#define NBATCH 512
#define DDIM 256

// ---- fused conv+pointwise config ----
#define RAD 160
#define TAPS 321                 // truncated Gaussian: tail mass ~1e-7
#define CHUNK 2048
#define CBLK 256
#define TPO 8
#define HALO_L 176               // 16 extra left so v_s[i0-1] is computable
#define WIN (HALO_L + CHUNK + RAD + 16)   // 2400
#define NGRP (WIN / 8)                    // 300 groups of 8 floats
#define LDSZ (NGRP * 9)                   // odd stride 9: bank-bijective b32 reads
#define LSWZ9(x) ((x) + ((x) >> 3))       // float x -> lds index (group g at 9g)

// output element offsets (flat concat in reference return order)
#define O0  0            // dv_out sliced  512*7700
#define O1  3942400      // dv_t           512*8000
#define O2  8038400      // dv2_t          512*8000
#define O3  12134400     // a              512
#define O4  12134912     // k*1000        512
#define O5  12135424     // epsilon        512
#define O6  12135936     // gamma          512
#define O7  12136448     // t_             512*8000
#define O8  16232448     // dv_l           512*8001
#define O9  20328960     // dv_r           512*8001
#define O10 24425472     // t_out          512*8000

// unaligned-capable 16B vector (dv_l/dv_r rows are 8001 floats -> 4B aligned)
typedef float f4u __attribute__((vector_size(16), aligned(4)));

// ---------------- params: k,a,eps,gamma = clip(relu(b@w.T + bias), lo, hi) ----
__global__ __launch_bounds__(256) void pc_params_kernel(
    const float* __restrict__ b,
    const float* __restrict__ kw, const float* __restrict__ kb,
    const float* __restrict__ aw, const float* __restrict__ ab,
    const float* __restrict__ ew, const float* __restrict__ eb,
    const float* __restrict__ gw, const float* __restrict__ gb,
    float* __restrict__ out3, float* __restrict__ out4,
    float* __restrict__ out5, float* __restrict__ out6,
    float* __restrict__ wsp)
{
    __shared__ float4 red[256];
    const int row = blockIdx.x;
    const int d = threadIdx.x;
    const float bv = b[row * DDIM + d];
    red[d] = make_float4(bv * kw[d], bv * aw[d], bv * ew[d], bv * gw[d]);
    __syncthreads();
    for (int s2 = 128; s2 > 0; s2 >>= 1) {
        if (d < s2) {
            float4 o = red[d + s2];
            red[d].x += o.x; red[d].y += o.y; red[d].z += o.z; red[d].w += o.w;
        }
        __syncthreads();
    }
    if (d == 0) {
        float4 s = red[0];
        float k = fminf(fmaxf(fmaxf(s.x + kb[0], 0.0f), 0.1f),   1.0f);
        float a = fminf(fmaxf(fmaxf(s.y + ab[0], 0.0f), 0.001f), 0.1f);
        float e = fminf(fmaxf(fmaxf(s.z + eb[0], 0.0f), 0.005f), 0.1f);
        float g = fminf(fmaxf(fmaxf(s.w + gb[0], 0.0f), 0.5f),   2.0f);
        out3[row] = a;
        out4[row] = k * 1000.0f;
        out5[row] = e;
        out6[row] = g;
        wsp[row]          = k;
        wsp[512 + row]    = a;
        wsp[1024 + row]   = e;
        wsp[1536 + row]   = g;
    }
}

// 8 taps x 8 outputs; window floats = L[0..7] ++ H[0..7]; all indices static
__device__ __forceinline__ void octave(const float* __restrict__ wbase,
                                       const float L[8], const float H[8],
                                       float acc[8])
{
    const float4 w0 = *(const float4*)(wbase);
    const float4 w1 = *(const float4*)(wbase + 4);
    const float w[8] = {w0.x, w0.y, w0.z, w0.w, w1.x, w1.y, w1.z, w1.w};
#pragma unroll
    for (int c = 0; c < 8; ++c) {
#pragma unroll
        for (int t = 0; t < 8; ++t) {
            const int s = c + t;
            acc[t] += w[c] * ((s < 8) ? L[s] : H[s - 8]);
        }
    }
}

// -------- fused: truncated-Gaussian FIR + finite diffs + physics + outputs ---
__global__ __launch_bounds__(CBLK, 5) void pc_fused_kernel(
    const float* __restrict__ v,
    const float* __restrict__ wsp,
    const int* __restrict__ use_cond,
    float* __restrict__ out0, float* __restrict__ out1,
    float* __restrict__ out2, float* __restrict__ out7,
    float* __restrict__ dvl,  float* __restrict__ dvr,
    float* __restrict__ out10)
{
    __shared__ float lds[LDSZ];                 // 2700 floats, stride-9 groups
    __shared__ __align__(16) float wlds[TAPS + 7];
    __shared__ float eRw[4], eLw[4];            // cross-wave edge exchange

    const int row = blockIdx.y;
    const int i0 = blockIdx.x * CHUNK;
    const int tid = threadIdx.x;
    const float* vrow = v + (long)row * SLEN;

    // weights into LDS: w[j] = exp(-(j-160)^2/1800) / (sigma*sqrt(2*pi))
    for (int j = tid; j < TAPS; j += CBLK) {
        const float d = (float)(j - RAD);
        wlds[j] = expf(d * d * (-1.0f / 1800.0f)) * (float)(1.0 / 75.19884823893001);
    }

    // stage window [i0-176, i0-176+2400): aligned float4 global loads
    // (st is 16B-aligned: i0 % 2048 == 0, 176 % 16 == 0, row stride 8000 % 4 == 0)
    const int st = i0 - HALO_L;
    for (int base = 4 * tid; base < WIN; base += 4 * CBLK) {
        const int g = st + base;
        float4 val;
        if (g >= 0 && g + 3 < SLEN) {
            val = *(const float4*)(vrow + g);
        } else {
            val.x = (g     >= 0 && g     < SLEN) ? vrow[g]     : 0.0f;
            val.y = (g + 1 >= 0 && g + 1 < SLEN) ? vrow[g + 1] : 0.0f;
            val.z = (g + 2 >= 0 && g + 2 < SLEN) ? vrow[g + 2] : 0.0f;
            val.w = (g + 3 >= 0 && g + 3 < SLEN) ? vrow[g + 3] : 0.0f;
        }
        lds[LSWZ9(base)]     = val.x;
        lds[LSWZ9(base + 1)] = val.y;
        lds[LSWZ9(base + 2)] = val.z;
        lds[LSWZ9(base + 3)] = val.w;
    }
    __syncthreads();

    // FIR: thread outputs i = i0 + 8*tid + t ; window idx x = 8*tid+16 + j + t
    // octave m uses window groups (tid+2+m), (tid+3+m); group n at lds[9n..9n+8)
    float acc[TPO];
#pragma unroll
    for (int t = 0; t < TPO; ++t) acc[t] = 0.0f;

    float B0[8], B1[8], B2[8], B3[8];
#define LOADG(dst, n) { const float* _p = lds + 9 * (n); \
    _Pragma("unroll") for (int _k = 0; _k < 8; ++_k) dst[_k] = _p[_k]; }

    LOADG(B0, tid + 2)
    LOADG(B1, tid + 3)
    LOADG(B2, tid + 4)
    LOADG(B3, tid + 5)

#pragma unroll 1
    for (int q = 0; q < 9; ++q) {
        const int m = 4 * q;
        octave(wlds + 8 * m,      B0, B1, acc); LOADG(B0, tid + 6 + m)
        octave(wlds + 8 * m + 8,  B1, B2, acc); LOADG(B1, tid + 7 + m)
        octave(wlds + 8 * m + 16, B2, B3, acc); LOADG(B2, tid + 8 + m)
        octave(wlds + 8 * m + 24, B3, B0, acc); LOADG(B3, tid + 9 + m)
    }
    // octaves 36..39 + final tap j=320 (B0 reloaded once more: group tid+42)
    octave(wlds + 288, B0, B1, acc); LOADG(B0, tid + 42)
    octave(wlds + 296, B1, B2, acc);
    octave(wlds + 304, B2, B3, acc);
    octave(wlds + 312, B3, B0, acc);
    {
        const float wl = wlds[TAPS - 1];
#pragma unroll
        for (int t = 0; t < TPO; ++t) acc[t] += wl * B0[t];
    }

    // block-edge v_s values: wave-parallel dot + butterfly reduce
    float leftE = 0.0f, rightE = 0.0f;
    const int lane = tid & 63;
    const int wid  = tid >> 6;
    if (tid < 64) {          // v_s[i0-1]: win idx 15+j
        float p = 0.0f;
        for (int j = lane; j < TAPS; j += 64) {
            const int x = 15 + j;
            p += wlds[j] * lds[LSWZ9(x)];
        }
#pragma unroll
        for (int off = 32; off > 0; off >>= 1) p += __shfl_xor(p, off, 64);
        leftE = p;
    }
    if (tid >= CBLK - 64) {  // v_s[i0+2048]: win idx 2064+j
        float p = 0.0f;
        for (int j = lane; j < TAPS; j += 64) {
            const int x = 2064 + j;
            p += wlds[j] * lds[LSWZ9(x)];
        }
#pragma unroll
        for (int off = 32; off > 0; off >>= 1) p += __shfl_xor(p, off, 64);
        rightE = p;
    }

    // neighbor v_s exchange: shfl within wave, tiny LDS across waves
    if (lane == 63) eRw[wid] = acc[7];
    if (lane == 0)  eLw[wid] = acc[0];
    __syncthreads();
    const float up = __shfl_up(acc[7], 1, 64);
    const float dn = __shfl_down(acc[0], 1, 64);
    const float eRp = (lane == 0)  ? ((wid == 0) ? leftE  : eRw[wid - 1]) : up;
    const float eLn = (lane == 63) ? ((wid == 3) ? rightE : eLw[wid + 1]) : dn;

    // physics epilogue
    const float kk = wsp[row];
    const float aa = wsp[512 + row];
    const float ee = wsp[1024 + row];
    const float gg = wsp[1536 + row];
    const int uc = *use_cond;

    constexpr float DT = 1.6f / 7999.0f;
    constexpr float C1 = 1.0f / (2.0f * DT);
    constexpr float C2 = 1.0f / (DT * DT);

    const int i8 = i0 + 8 * tid;
    float dvt8[TPO], dv28[TPO], lg8[TPO];
#pragma unroll
    for (int t = 0; t < TPO; ++t) {
        const int i = i8 + t;
        const float vc = acc[t];
        float vm = (t == 0) ? eRp : acc[t - 1];
        float vp = (t == TPO - 1) ? eLn : acc[t + 1];
        if (i == 0) vm = 0.0f;
        if (i == SLEN - 1) vp = 0.0f;

        const float dv_t = (vp - vm) * C1;
        const float dv2  = (vp + vm - 2.0f * vc) * C2;

        float vn = (vc == 0.0f) ? 0.001f : vc;
        float inv_v = 1.0f / vn;
        if (inv_v != inv_v) inv_v = 0.0f;

        const float term_l1 = vc * kk * dv_t * (1.0f - 2.0f * vc + aa);
        const float term_l2 = inv_v * dv_t * dv_t;
        const float term_lt = 1000.0f * term_l1 + term_l2 - dv2;
        const float term_r1 = vc * (vc - gg * kk * 1000.0f * (1.0f - vc) * (vc - aa));
        const float term_rt = ee * (term_r1 + gg * dv_t);
        float dvo = term_lt - term_rt;
        if (uc) {
            if (vrow[i < SLEN ? i : 0] <= 0.0f) dvo = 0.0f;
        }
        dvt8[t] = dv_t;
        dv28[t] = dv2;
        lg8[t]  = logf(dvo * dvo + 1e-5f);
    }

    if (i8 < SLEN) {   // threads are entirely in-range or entirely OOB (8|8000)
        const long rs = (long)row * SLEN + i8;
        *(float4*)(out1 + rs)     = make_float4(dvt8[0], dvt8[1], dvt8[2], dvt8[3]);
        *(float4*)(out1 + rs + 4) = make_float4(dvt8[4], dvt8[5], dvt8[6], dvt8[7]);
        *(float4*)(out2 + rs)     = make_float4(dv28[0], dv28[1], dv28[2], dv28[3]);
        *(float4*)(out2 + rs + 4) = make_float4(dv28[4], dv28[5], dv28[6], dv28[7]);
        const float4 c16 = make_float4(1.6f, 1.6f, 1.6f, 1.6f);
        *(float4*)(out7 + rs)      = c16;
        *(float4*)(out7 + rs + 4)  = c16;
        *(float4*)(out10 + rs)     = c16;
        *(float4*)(out10 + rs + 4) = c16;

        const long rb = (long)row * (SLEN + 1) + i8;
        f4u a0 = {acc[0], acc[1], acc[2], acc[3]};
        f4u a1 = {acc[4], acc[5], acc[6], acc[7]};
        *(f4u*)(dvr + rb)     = a0;          // dv_r[i] = v_s[i]
        *(f4u*)(dvr + rb + 4) = a1;
        *(f4u*)(dvl + rb + 1) = a0;          // dv_l[i+1] = v_s[i]
        *(f4u*)(dvl + rb + 5) = a1;
        if (i8 == 0)        dvl[(long)row * (SLEN + 1)] = 0.0f;
        if (i8 == SLEN - 8) dvr[(long)row * (SLEN + 1) + SLEN] = 0.0f;

        const long r0 = (long)row * 7700;
        // vectorized interior: 8-block fully inside [100,950) or [1050,7900)
        int obase = -1;
        if (i8 >= 104 && i8 <= 936)        obase = i8 - 100;
        else if (i8 >= 1056 && i8 <= 7888) obase = i8 - 200;
        if (obase >= 0) {
            f4u l0 = {lg8[0], lg8[1], lg8[2], lg8[3]};
            f4u l1 = {lg8[4], lg8[5], lg8[6], lg8[7]};
            *(f4u*)(out0 + r0 + obase)     = l0;
            *(f4u*)(out0 + r0 + obase + 4) = l1;
        } else {
#pragma unroll
            for (int t = 0; t < TPO; ++t) {
                const int i = i8 + t;
                if (i >= 100 && i < 950)        out0[r0 + (i - 100)] = lg8[t];
                else if (i >= 1050 && i < 7900) out0[r0 + (i - 200)] = lg8[t];
            }
        }
    }
}

extern "C" void kernel_launch(void* const* d_in, const int* in_sizes, int n_in,
                              void* d_out, int out_size, void* d_ws, size_t ws_size,
                              hipStream_t stream)
{
    const float* v_out = (const float*)d_in[0];
    const float* b  = (const float*)d_in[1];
    const float* kw = (const float*)d_in[2];
    const float* kb = (const float*)d_in[3];
    const float* aw = (const float*)d_in[4];
    const float* ab = (const float*)d_in[5];
    const float* ew = (const float*)d_in[6];
    const float* eb = (const float*)d_in[7];
    const float* gw = (const float*)d_in[8];
    const float* gb = (const float*)d_in[9];
    const int* use_cond = (const int*)d_in[10];
    float* out = (float*)d_out;
    float* wsp = (float*)d_ws;   // 2048 floats: k,a,eps,gamma per row

    pc_params_kernel<<<NBATCH, 256, 0, stream>>>(
        b, kw, kb, aw, ab, ew, eb, gw, gb,
        out + O3, out + O4, out + O5, out + O6, wsp);

    pc_fused_kernel<<<dim3((SLEN + CHUNK - 1) / CHUNK, NBATCH), CBLK, 0, stream>>>(
        v_out, wsp, use_cond,
        out + O0, out + O1, out + O2, out + O7,
        out + O8, out + O9, out + O10);
}

// Round 4
// 180.883 us; speedup vs baseline: 1.7162x; 1.7162x over previous
//
#include <hip/hip_runtime.h>
#include <math.h>

#define SLEN 8000
#define NBATCH 512
#define DDIM 256

// ---- fused conv+pointwise config ----
#define RAD 160
#define TAPS 321                 // truncated Gaussian: tail mass ~1e-7
#define CHUNK 2048
#define CBLK 256
#define TPO 8
#define HALO_L 176               // 16 extra left so v_s[i0-1] is computable
#define WIN (HALO_L + CHUNK + RAD + 16)   // 2400
#define NGRP (WIN / 8)                    // 300 groups of 8 floats
#define LDSZ (NGRP * 9)                   // odd stride 9: bank-bijective b32 reads
#define LSWZ9(x) ((x) + ((x) >> 3))       // float x -> lds index (group g at 9g)
// occupancy governor: 3 blocks/CU (4+ blocks/CU thrashes L2 with partial-line
// writes: round-3 measured FETCH 9->266 MB, WRITE 112->381 MB at 5 blocks/CU)
#define LDSPAD 1400

// output element offsets (flat concat in reference return order)
#define O0  0            // dv_out sliced  512*7700
#define O1  3942400      // dv_t           512*8000
#define O2  8038400      // dv2_t          512*8000
#define O3  12134400     // a              512
#define O4  12134912     // k*1000        512
#define O5  12135424     // epsilon        512
#define O6  12135936     // gamma          512
#define O7  12136448     // t_             512*8000
#define O8  16232448     // dv_l           512*8001
#define O9  20328960     // dv_r           512*8001
#define O10 24425472     // t_out          512*8000

// unaligned-capable 16B vector (dv_l/dv_r rows are 8001 floats -> 4B aligned)
typedef float f4u __attribute__((vector_size(16), aligned(4)));

// ---------------- params: k,a,eps,gamma = clip(relu(b@w.T + bias), lo, hi) ----
__global__ __launch_bounds__(256) void pc_params_kernel(
    const float* __restrict__ b,
    const float* __restrict__ kw, const float* __restrict__ kb,
    const float* __restrict__ aw, const float* __restrict__ ab,
    const float* __restrict__ ew, const float* __restrict__ eb,
    const float* __restrict__ gw, const float* __restrict__ gb,
    float* __restrict__ out3, float* __restrict__ out4,
    float* __restrict__ out5, float* __restrict__ out6,
    float* __restrict__ wsp)
{
    __shared__ float4 red[256];
    const int row = blockIdx.x;
    const int d = threadIdx.x;
    const float bv = b[row * DDIM + d];
    red[d] = make_float4(bv * kw[d], bv * aw[d], bv * ew[d], bv * gw[d]);
    __syncthreads();
    for (int s2 = 128; s2 > 0; s2 >>= 1) {
        if (d < s2) {
            float4 o = red[d + s2];
            red[d].x += o.x; red[d].y += o.y; red[d].z += o.z; red[d].w += o.w;
        }
        __syncthreads();
    }
    if (d == 0) {
        float4 s = red[0];
        float k = fminf(fmaxf(fmaxf(s.x + kb[0], 0.0f), 0.1f),   1.0f);
        float a = fminf(fmaxf(fmaxf(s.y + ab[0], 0.0f), 0.001f), 0.1f);
        float e = fminf(fmaxf(fmaxf(s.z + eb[0], 0.0f), 0.005f), 0.1f);
        float g = fminf(fmaxf(fmaxf(s.w + gb[0], 0.0f), 0.5f),   2.0f);
        out3[row] = a;
        out4[row] = k * 1000.0f;
        out5[row] = e;
        out6[row] = g;
        wsp[row]          = k;
        wsp[512 + row]    = a;
        wsp[1024 + row]   = e;
        wsp[1536 + row]   = g;
    }
}

// 8 taps x 8 outputs; window floats = L[0..7] ++ H[0..7]; all indices static
__device__ __forceinline__ void octave(const float* __restrict__ wbase,
                                       const float L[8], const float H[8],
                                       float acc[8])
{
    const float4 w0 = *(const float4*)(wbase);
    const float4 w1 = *(const float4*)(wbase + 4);
    const float w[8] = {w0.x, w0.y, w0.z, w0.w, w1.x, w1.y, w1.z, w1.w};
#pragma unroll
    for (int c = 0; c < 8; ++c) {
#pragma unroll
        for (int t = 0; t < 8; ++t) {
            const int s = c + t;
            acc[t] += w[c] * ((s < 8) ? L[s] : H[s - 8]);
        }
    }
}

// -------- fused: truncated-Gaussian FIR + finite diffs + physics + outputs ---
__global__ __launch_bounds__(CBLK) void pc_fused_kernel(
    const float* __restrict__ v,
    const float* __restrict__ wsp,
    const int* __restrict__ use_cond,
    float* __restrict__ out0, float* __restrict__ out1,
    float* __restrict__ out2, float* __restrict__ out7,
    float* __restrict__ dvl,  float* __restrict__ dvr,
    float* __restrict__ out10)
{
    __shared__ float lds[LDSZ + LDSPAD];        // pad -> 17.9 KB -> 3 blocks/CU
    __shared__ __align__(16) float wlds[TAPS + 7];
    __shared__ float eRw[4], eLw[4];            // cross-wave edge exchange

    const int row = blockIdx.y;
    const int i0 = blockIdx.x * CHUNK;
    const int tid = threadIdx.x;
    const float* vrow = v + (long)row * SLEN;

    // weights into LDS: w[j] = exp(-(j-160)^2/1800) / (sigma*sqrt(2*pi))
    for (int j = tid; j < TAPS; j += CBLK) {
        const float d = (float)(j - RAD);
        wlds[j] = expf(d * d * (-1.0f / 1800.0f)) * (float)(1.0 / 75.19884823893001);
    }

    // stage window [i0-176, i0-176+2400): aligned float4 global loads
    // (st is 16B-aligned: i0 % 2048 == 0, 176 % 16 == 0, row stride 8000 % 4 == 0)
    const int st = i0 - HALO_L;
    for (int base = 4 * tid; base < WIN; base += 4 * CBLK) {
        const int g = st + base;
        float4 val;
        if (g >= 0 && g + 3 < SLEN) {
            val = *(const float4*)(vrow + g);
        } else {
            val.x = (g     >= 0 && g     < SLEN) ? vrow[g]     : 0.0f;
            val.y = (g + 1 >= 0 && g + 1 < SLEN) ? vrow[g + 1] : 0.0f;
            val.z = (g + 2 >= 0 && g + 2 < SLEN) ? vrow[g + 2] : 0.0f;
            val.w = (g + 3 >= 0 && g + 3 < SLEN) ? vrow[g + 3] : 0.0f;
        }
        lds[LSWZ9(base)]     = val.x;
        lds[LSWZ9(base + 1)] = val.y;
        lds[LSWZ9(base + 2)] = val.z;
        lds[LSWZ9(base + 3)] = val.w;
    }
    __syncthreads();

    // FIR: thread outputs i = i0 + 8*tid + t ; window idx x = 8*tid+16 + j + t
    // octave m uses window groups (tid+2+m), (tid+3+m); group n at lds[9n..9n+8)
    float acc[TPO];
#pragma unroll
    for (int t = 0; t < TPO; ++t) acc[t] = 0.0f;

    float B0[8], B1[8], B2[8], B3[8];
#define LOADG(dst, n) { const float* _p = lds + 9 * (n); \
    _Pragma("unroll") for (int _k = 0; _k < 8; ++_k) dst[_k] = _p[_k]; }

    LOADG(B0, tid + 2)
    LOADG(B1, tid + 3)
    LOADG(B2, tid + 4)
    LOADG(B3, tid + 5)

#pragma unroll 1
    for (int q = 0; q < 9; ++q) {
        const int m = 4 * q;
        octave(wlds + 8 * m,      B0, B1, acc); LOADG(B0, tid + 6 + m)
        octave(wlds + 8 * m + 8,  B1, B2, acc); LOADG(B1, tid + 7 + m)
        octave(wlds + 8 * m + 16, B2, B3, acc); LOADG(B2, tid + 8 + m)
        octave(wlds + 8 * m + 24, B3, B0, acc); LOADG(B3, tid + 9 + m)
    }
    // octaves 36..39 + final tap j=320 (B0 reloaded once more: group tid+42)
    octave(wlds + 288, B0, B1, acc); LOADG(B0, tid + 42)
    octave(wlds + 296, B1, B2, acc);
    octave(wlds + 304, B2, B3, acc);
    octave(wlds + 312, B3, B0, acc);
    {
        const float wl = wlds[TAPS - 1];
#pragma unroll
        for (int t = 0; t < TPO; ++t) acc[t] += wl * B0[t];
    }

    // block-edge v_s values: wave-parallel dot + butterfly reduce
    float leftE = 0.0f, rightE = 0.0f;
    const int lane = tid & 63;
    const int wid  = tid >> 6;
    if (tid < 64) {          // v_s[i0-1]: win idx 15+j
        float p = 0.0f;
        for (int j = lane; j < TAPS; j += 64) {
            const int x = 15 + j;
            p += wlds[j] * lds[LSWZ9(x)];
        }
#pragma unroll
        for (int off = 32; off > 0; off >>= 1) p += __shfl_xor(p, off, 64);
        leftE = p;
    }
    if (tid >= CBLK - 64) {  // v_s[i0+2048]: win idx 2064+j
        float p = 0.0f;
        for (int j = lane; j < TAPS; j += 64) {
            const int x = 2064 + j;
            p += wlds[j] * lds[LSWZ9(x)];
        }
#pragma unroll
        for (int off = 32; off > 0; off >>= 1) p += __shfl_xor(p, off, 64);
        rightE = p;
    }

    // neighbor v_s exchange: shfl within wave, tiny LDS across waves
    if (lane == 63) eRw[wid] = acc[7];
    if (lane == 0)  eLw[wid] = acc[0];
    __syncthreads();
    const float up = __shfl_up(acc[7], 1, 64);
    const float dn = __shfl_down(acc[0], 1, 64);
    const float eRp = (lane == 0)  ? ((wid == 0) ? leftE  : eRw[wid - 1]) : up;
    const float eLn = (lane == 63) ? ((wid == 3) ? rightE : eLw[wid + 1]) : dn;

    // physics epilogue
    const float kk = wsp[row];
    const float aa = wsp[512 + row];
    const float ee = wsp[1024 + row];
    const float gg = wsp[1536 + row];
    const int uc = *use_cond;

    constexpr float DT = 1.6f / 7999.0f;
    constexpr float C1 = 1.0f / (2.0f * DT);
    constexpr float C2 = 1.0f / (DT * DT);

    const int i8 = i0 + 8 * tid;
    float dvt8[TPO], dv28[TPO], lg8[TPO];
#pragma unroll
    for (int t = 0; t < TPO; ++t) {
        const int i = i8 + t;
        const float vc = acc[t];
        float vm = (t == 0) ? eRp : acc[t - 1];
        float vp = (t == TPO - 1) ? eLn : acc[t + 1];
        if (i == 0) vm = 0.0f;
        if (i == SLEN - 1) vp = 0.0f;

        const float dv_t = (vp - vm) * C1;
        const float dv2  = (vp + vm - 2.0f * vc) * C2;

        float vn = (vc == 0.0f) ? 0.001f : vc;
        float inv_v = 1.0f / vn;
        if (inv_v != inv_v) inv_v = 0.0f;

        const float term_l1 = vc * kk * dv_t * (1.0f - 2.0f * vc + aa);
        const float term_l2 = inv_v * dv_t * dv_t;
        const float term_lt = 1000.0f * term_l1 + term_l2 - dv2;
        const float term_r1 = vc * (vc - gg * kk * 1000.0f * (1.0f - vc) * (vc - aa));
        const float term_rt = ee * (term_r1 + gg * dv_t);
        float dvo = term_lt - term_rt;
        if (uc) {
            if (vrow[i < SLEN ? i : 0] <= 0.0f) dvo = 0.0f;
        }
        dvt8[t] = dv_t;
        dv28[t] = dv2;
        lg8[t]  = logf(dvo * dvo + 1e-5f);
    }

    if (i8 < SLEN) {   // threads are entirely in-range or entirely OOB (8|8000)
        const long rs = (long)row * SLEN + i8;
        *(float4*)(out1 + rs)     = make_float4(dvt8[0], dvt8[1], dvt8[2], dvt8[3]);
        *(float4*)(out1 + rs + 4) = make_float4(dvt8[4], dvt8[5], dvt8[6], dvt8[7]);
        *(float4*)(out2 + rs)     = make_float4(dv28[0], dv28[1], dv28[2], dv28[3]);
        *(float4*)(out2 + rs + 4) = make_float4(dv28[4], dv28[5], dv28[6], dv28[7]);
        const float4 c16 = make_float4(1.6f, 1.6f, 1.6f, 1.6f);
        *(float4*)(out7 + rs)      = c16;
        *(float4*)(out7 + rs + 4)  = c16;
        *(float4*)(out10 + rs)     = c16;
        *(float4*)(out10 + rs + 4) = c16;

        const long rb = (long)row * (SLEN + 1) + i8;
        f4u a0 = {acc[0], acc[1], acc[2], acc[3]};
        f4u a1 = {acc[4], acc[5], acc[6], acc[7]};
        *(f4u*)(dvr + rb)     = a0;          // dv_r[i] = v_s[i]
        *(f4u*)(dvr + rb + 4) = a1;
        *(f4u*)(dvl + rb + 1) = a0;          // dv_l[i+1] = v_s[i]
        *(f4u*)(dvl + rb + 5) = a1;
        if (i8 == 0)        dvl[(long)row * (SLEN + 1)] = 0.0f;
        if (i8 == SLEN - 8) dvr[(long)row * (SLEN + 1) + SLEN] = 0.0f;

        const long r0 = (long)row * 7700;
        // vectorized interior: 8-block fully inside [100,950) or [1050,7900)
        int obase = -1;
        if (i8 >= 104 && i8 <= 936)        obase = i8 - 100;
        else if (i8 >= 1056 && i8 <= 7888) obase = i8 - 200;
        if (obase >= 0) {
            f4u l0 = {lg8[0], lg8[1], lg8[2], lg8[3]};
            f4u l1 = {lg8[4], lg8[5], lg8[6], lg8[7]};
            *(f4u*)(out0 + r0 + obase)     = l0;
            *(f4u*)(out0 + r0 + obase + 4) = l1;
        } else {
#pragma unroll
            for (int t = 0; t < TPO; ++t) {
                const int i = i8 + t;
                if (i >= 100 && i < 950)        out0[r0 + (i - 100)] = lg8[t];
                else if (i >= 1050 && i < 7900) out0[r0 + (i - 200)] = lg8[t];
            }
        }
    }
}

extern "C" void kernel_launch(void* const* d_in, const int* in_sizes, int n_in,
                              void* d_out, int out_size, void* d_ws, size_t ws_size,
                              hipStream_t stream)
{
    const float* v_out = (const float*)d_in[0];
    const float* b  = (const float*)d_in[1];
    const float* kw = (const float*)d_in[2];
    const float* kb = (const float*)d_in[3];
    const float* aw = (const float*)d_in[4];
    const float* ab = (const float*)d_in[5];
    const float* ew = (const float*)d_in[6];
    const float* eb = (const float*)d_in[7];
    const float* gw = (const float*)d_in[8];
    const float* gb = (const float*)d_in[9];
    const int* use_cond = (const int*)d_in[10];
    float* out = (float*)d_out;
    float* wsp = (float*)d_ws;   // 2048 floats: k,a,eps,gamma per row

    pc_params_kernel<<<NBATCH, 256, 0, stream>>>(
        b, kw, kb, aw, ab, ew, eb, gw, gb,
        out + O3, out + O4, out + O5, out + O6, wsp);

    pc_fused_kernel<<<dim3((SLEN + CHUNK - 1) / CHUNK, NBATCH), CBLK, 0, stream>>>(
        v_out, wsp, use_cond,
        out + O0, out + O1, out + O2, out + O7,
        out + O8, out + O9, out + O10);
}